// Round 5
// baseline (102.335 us; speedup 1.0000x reference)
//
#include <hip/hip_runtime.h>

// spikes = (floor(v0 + cumsum(relu(x)*DT)) - floor(prev)) / DT, f64 scan.
// (f32 scan flips floors vs the f64 np reference — R0/R1; f64 segment
// reassociation ~1e-16, validated absmax 0.0 in R3/R4.)
//
// R3 fused (57.4us) vs R4 two-kernel float4 (64.0us): the split lost to
// launch overhead; both run ~7.0 TB/s aggregate (= fillBuffer's 7.1).
// This round: fused structure + (a) prefetch depth 32, (b) phase-2 first
// chunk prefetched BEFORE the barrier, (c) nontemporal output stores so
// 134 MB of spikes don't write-allocate and evict the LLC-resident input.

#pragma clang fp contract(off)   // np rounds rate before accumulating: no FMA

constexpr int B = 16;
constexpr int T = 2048;
constexpr int D = 1024;
constexpr int NSEG = 16;          // waves per block == T segments
constexpr int TSEG = T / NSEG;    // 128 steps per segment
constexpr int U = 32;             // prefetch chunk depth (dwords in flight)

__global__ __launch_bounds__(1024, 4)   // 16 waves/CU -> VGPR capped at 128
void spike_scan_kernel(const float* __restrict__ in,
                       const float* __restrict__ state,
                       float* __restrict__ out) {
  const int lane = threadIdx.x & 63;
  const int wave = threadIdx.x >> 6;              // segment index 0..15
  const int id = blockIdx.x * 64 + lane;          // chain id; lane = consec d
  const int b = id >> 10;                         // D = 1024
  const int d = id & (D - 1);
  const size_t base = (size_t)b * T * D + d + (size_t)wave * TSEG * D;
  const float* __restrict__ ip = in + base;
  float* __restrict__ op = out + base;

  __shared__ double segsum[NSEG][64];             // 8 KB

  // ---- Phase 1: in-order f64 sum of rates over this wave's segment ----
  double ssum = 0.0;
  for (int t = 0; t < TSEG; t += U) {
    float buf[U];
#pragma unroll
    for (int u = 0; u < U; ++u) buf[u] = ip[(size_t)(t + u) * D];
#pragma unroll
    for (int u = 0; u < U; ++u)
      ssum += (double)fmaxf(buf[u], 0.0f) * 0.001;  // == fmax((double)x,0)*1e-3
  }
  segsum[wave][lane] = ssum;

  // Prefetch phase-2's first chunk BEFORE the barrier (addr-independent).
  float pA[U], pB[U];
#pragma unroll
  for (int u = 0; u < U; ++u) pA[u] = ip[(size_t)u * D];

  __syncthreads();

  // ---- Phase 2: segment prefix (in order), then emit this segment ----
  const double v0 = (double)state[id];
  double s = 0.0;                                 // rate-sum before my segment
  for (int w = 0; w < wave; ++w) s += segsum[w][lane];
  double prev = floor(v0 + s);                    // wave 0: floor(v0)

  for (int t = 0; t < TSEG; t += 2 * U) {
#pragma unroll
    for (int u = 0; u < U; ++u) pB[u] = ip[(size_t)(t + U + u) * D];
#pragma unroll
    for (int u = 0; u < U; ++u) {
      s += (double)fmaxf(pA[u], 0.0f) * 0.001;
      const double fl = floor(v0 + s);
      __builtin_nontemporal_store((float)((fl - prev) * 1000.0),
                                  &op[(size_t)(t + u) * D]);
      prev = fl;
    }
    if (t + 2 * U < TSEG) {
#pragma unroll
      for (int u = 0; u < U; ++u) pA[u] = ip[(size_t)(t + 2 * U + u) * D];
    }
#pragma unroll
    for (int u = 0; u < U; ++u) {
      s += (double)fmaxf(pB[u], 0.0f) * 0.001;
      const double fl = floor(v0 + s);
      __builtin_nontemporal_store((float)((fl - prev) * 1000.0),
                                  &op[(size_t)(t + U + u) * D]);
      prev = fl;
    }
  }
}

extern "C" void kernel_launch(void* const* d_in, const int* in_sizes, int n_in,
                              void* d_out, int out_size, void* d_ws, size_t ws_size,
                              hipStream_t stream) {
  const float* in = (const float*)d_in[0];     // [B, T, D] f32
  const float* st = (const float*)d_in[1];     // [B, D]    f32
  float* out = (float*)d_out;                  // [B, T, D] f32

  // 16384 chains / 64 lanes = 256 blocks; 16 waves each (one per T-segment).
  dim3 grid(B * D / 64);
  dim3 block(NSEG * 64);
  spike_scan_kernel<<<grid, block, 0, stream>>>(in, st, out);
}

// Round 6
// 57.711 us; speedup vs baseline: 1.7732x; 1.7732x over previous
//
#include <hip/hip_runtime.h>

// spikes = (floor(v0 + cumsum(relu(x)*DT)) - floor(prev)) / DT, f64 scan.
// (f32 scan flips floors vs the f64 np reference — R0/R1; f64 segment
// reassociation ~1e-16, validated absmax 0.0 in R3/R4.)
//
// History: R3 fused 16-seg = 57.4us (occupancy 35%, latency-bound).
// R4 two-kernel float4 = 64us (launch overhead). R5 nontemporal stores =
// 102us (WRITE_SIZE +69% — write amplification; NEVER nt-store this output).
//
// R6: same fused structure, but 2x wave parallelism: 512 blocks, each
// covering 32 chains x 32 segments (TSEG=64). Each wave's lo/hi half-wave
// handles segments w and w+16 (128B contiguous per half — coalesced).
// VGPR<=64 -> 2 blocks/CU -> up to 32 waves/CU in flight.

#pragma clang fp contract(off)   // np rounds rate before accumulating: no FMA

constexpr int B = 16;
constexpr int T = 2048;
constexpr int D = 1024;
constexpr int NSEG = 32;          // segments along T
constexpr int TSEG = T / NSEG;    // 64 steps per segment
constexpr int CPB = 32;           // chains per block
constexpr int U = 16;             // prefetch chunk depth

__global__ __launch_bounds__(1024, 4)
void spike_scan_kernel(const float* __restrict__ in,
                       const float* __restrict__ state,
                       float* __restrict__ out) {
  const int lane = threadIdx.x & 63;
  const int wave = threadIdx.x >> 6;              // 0..15
  const int half = lane >> 5;                     // 0 = lo half-wave, 1 = hi
  const int sub  = lane & 31;                     // chain within block
  const int seg  = wave + 16 * half;              // segment 0..31

  const int c = blockIdx.x * CPB + sub;           // chain id
  const int b = c >> 10;                          // D = 1024
  const int d = c & (D - 1);
  const size_t base = (size_t)b * T * D + d + (size_t)seg * TSEG * D;
  const float* __restrict__ ip = in + base;
  float* __restrict__ op = out + base;

  __shared__ double segsum[NSEG][CPB];            // 8 KB

  // ---- Phase 1: in-order f64 sum of rates over this segment ----
  double ssum = 0.0;
  {
    float bufA[U], bufB[U];
#pragma unroll
    for (int u = 0; u < U; ++u) bufA[u] = ip[(size_t)u * D];
    for (int t = 0; t < TSEG; t += 2 * U) {
#pragma unroll
      for (int u = 0; u < U; ++u) bufB[u] = ip[(size_t)(t + U + u) * D];
#pragma unroll
      for (int u = 0; u < U; ++u)
        ssum += (double)fmaxf(bufA[u], 0.0f) * 0.001;
      if (t + 2 * U < TSEG) {
#pragma unroll
        for (int u = 0; u < U; ++u) bufA[u] = ip[(size_t)(t + 2 * U + u) * D];
      }
#pragma unroll
      for (int u = 0; u < U; ++u)
        ssum += (double)fmaxf(bufB[u], 0.0f) * 0.001;
    }
  }
  segsum[seg][sub] = ssum;
  __syncthreads();

  // ---- Phase 2: in-order prefix over preceding segments, then emit ----
  const double v0 = (double)state[c];
  double s = 0.0;
  for (int w = 0; w < seg; ++w) s += segsum[w][sub];
  double prev = floor(v0 + s);                    // seg 0: floor(v0)

  float bufA[U], bufB[U];
#pragma unroll
  for (int u = 0; u < U; ++u) bufA[u] = ip[(size_t)u * D];
  for (int t = 0; t < TSEG; t += 2 * U) {
#pragma unroll
    for (int u = 0; u < U; ++u) bufB[u] = ip[(size_t)(t + U + u) * D];
#pragma unroll
    for (int u = 0; u < U; ++u) {
      s += (double)fmaxf(bufA[u], 0.0f) * 0.001;
      const double fl = floor(v0 + s);
      op[(size_t)(t + u) * D] = (float)((fl - prev) * 1000.0);
      prev = fl;
    }
    if (t + 2 * U < TSEG) {
#pragma unroll
      for (int u = 0; u < U; ++u) bufA[u] = ip[(size_t)(t + 2 * U + u) * D];
    }
#pragma unroll
    for (int u = 0; u < U; ++u) {
      s += (double)fmaxf(bufB[u], 0.0f) * 0.001;
      const double fl = floor(v0 + s);
      op[(size_t)(t + U + u) * D] = (float)((fl - prev) * 1000.0);
      prev = fl;
    }
  }
}

extern "C" void kernel_launch(void* const* d_in, const int* in_sizes, int n_in,
                              void* d_out, int out_size, void* d_ws, size_t ws_size,
                              hipStream_t stream) {
  const float* in = (const float*)d_in[0];     // [B, T, D] f32
  const float* st = (const float*)d_in[1];     // [B, D]    f32
  float* out = (float*)d_out;                  // [B, T, D] f32

  // 16384 chains / 32 per block = 512 blocks x 1024 threads (16 waves):
  // 2 blocks/CU -> up to 32 waves/CU.
  dim3 grid(B * D / CPB);
  dim3 block(1024);
  spike_scan_kernel<<<grid, block, 0, stream>>>(in, st, out);
}